// Round 1
// baseline (229.126 us; speedup 1.0000x reference)
//
#include <hip/hip_runtime.h>
#include <math.h>

// Problem constants (B, S, E, WIN) = (8, 2048, 512, 11)
#define B_    8
#define S_    2048
#define E_    512
#define WIN_  11
#define WW    5              // WIN/2
#define FLATF (WIN_ * E_)    // 5632 floats per flat window
#define F4C   (FLATF / 4)    // 1408 float4 per W row
#define E4C   (E_ / 4)       // 128 float4 per x row

// One block per sequence position s. 256 threads = 4 waves.
// Phase 1: gates[b][w] = sigmoid( sum_f flat[b,f] * W[s,w,f] + bias[s,w] )
//   - thread t covers f4 = t + 256k slice; acc[8][11] in registers.
// Phase 2: out[b,s,e] = tanh( sum_w gates[b][w] * x[b, s-5+w, e] )
__global__ __launch_bounds__(256)
void win_attn_kernel(const float* __restrict__ x,
                     const float* __restrict__ W,
                     const float* __restrict__ bias,
                     float* __restrict__ out)
{
    const int s    = blockIdx.x;
    const int tid  = threadIdx.x;
    const int lane = tid & 63;
    const int wid  = tid >> 6;

    const float4* __restrict__ X4 = reinterpret_cast<const float4*>(x);
    const float4* __restrict__ W4 =
        reinterpret_cast<const float4*>(W) + (size_t)s * (size_t)(F4C * WIN_);

    float acc[B_][WIN_];
    #pragma unroll
    for (int b = 0; b < B_; ++b)
        #pragma unroll
        for (int w = 0; w < WIN_; ++w) acc[b][w] = 0.f;

    // ---- Phase 1: streamed dot products over f (W read exactly once) ----
    #pragma unroll 1
    for (int k = 0; k < 6; ++k) {
        const int f4 = tid + (k << 8);
        if (f4 < F4C) {
            float4 wv[WIN_];
            #pragma unroll
            for (int w = 0; w < WIN_; ++w) wv[w] = W4[w * F4C + f4];

            const int wp  = f4 >> 7;      // which window row (0..10)
            const int e4  = f4 & 127;     // float4 index within row
            const int row = s - WW + wp;
            const bool valid = (row >= 0) && (row < S_);

            #pragma unroll
            for (int b = 0; b < B_; ++b) {
                float4 xv = make_float4(0.f, 0.f, 0.f, 0.f);
                if (valid) xv = X4[((size_t)b * S_ + row) * E4C + e4];
                #pragma unroll
                for (int w = 0; w < WIN_; ++w) {
                    acc[b][w] = fmaf(xv.x, wv[w].x, acc[b][w]);
                    acc[b][w] = fmaf(xv.y, wv[w].y, acc[b][w]);
                    acc[b][w] = fmaf(xv.z, wv[w].z, acc[b][w]);
                    acc[b][w] = fmaf(xv.w, wv[w].w, acc[b][w]);
                }
            }
        }
    }

    // ---- wave-level butterfly reduction (all 64 lanes end with the sum) ----
    #pragma unroll
    for (int b = 0; b < B_; ++b)
        #pragma unroll
        for (int w = 0; w < WIN_; ++w) {
            float v = acc[b][w];
            v += __shfl_xor(v, 32, 64);
            v += __shfl_xor(v, 16, 64);
            v += __shfl_xor(v,  8, 64);
            v += __shfl_xor(v,  4, 64);
            v += __shfl_xor(v,  2, 64);
            v += __shfl_xor(v,  1, 64);
            acc[b][w] = v;
        }

    __shared__ float red[4][B_ * WIN_];
    __shared__ float gates[B_ * WIN_];

    if (lane == 0) {
        #pragma unroll
        for (int b = 0; b < B_; ++b)
            #pragma unroll
            for (int w = 0; w < WIN_; ++w)
                red[wid][b * WIN_ + w] = acc[b][w];
    }
    __syncthreads();

    if (tid < B_ * WIN_) {
        const int w = tid % WIN_;
        float v = red[0][tid] + red[1][tid] + red[2][tid] + red[3][tid];
        v += bias[s * WIN_ + w];
        gates[tid] = 1.f / (1.f + expf(-v));
    }
    __syncthreads();

    // ---- Phase 2: score + tanh, x rows re-read (L2/L3 hot) ----
    float4* __restrict__ OUT4 = reinterpret_cast<float4*>(out);
    #pragma unroll
    for (int it = 0; it < 4; ++it) {
        const int i  = tid + (it << 8);   // 0..1023 -> (b, e4)
        const int b  = i >> 7;
        const int e4 = i & 127;
        float4 sc = make_float4(0.f, 0.f, 0.f, 0.f);
        #pragma unroll
        for (int w = 0; w < WIN_; ++w) {
            const int row = s - WW + w;
            if (row >= 0 && row < S_) {
                const float g   = gates[b * WIN_ + w];
                const float4 xv = X4[((size_t)b * S_ + row) * E4C + e4];
                sc.x = fmaf(g, xv.x, sc.x);
                sc.y = fmaf(g, xv.y, sc.y);
                sc.z = fmaf(g, xv.z, sc.z);
                sc.w = fmaf(g, xv.w, sc.w);
            }
        }
        float4 o;
        o.x = tanhf(sc.x);
        o.y = tanhf(sc.y);
        o.z = tanhf(sc.z);
        o.w = tanhf(sc.w);
        OUT4[((size_t)b * S_ + s) * E4C + e4] = o;
    }
}

extern "C" void kernel_launch(void* const* d_in, const int* in_sizes, int n_in,
                              void* d_out, int out_size, void* d_ws, size_t ws_size,
                              hipStream_t stream)
{
    const float* x    = (const float*)d_in[0];
    const float* W    = (const float*)d_in[1];
    const float* bias = (const float*)d_in[2];
    float* out        = (float*)d_out;

    win_attn_kernel<<<dim3(S_), dim3(256), 0, stream>>>(x, W, bias, out);
}